// Round 1
// baseline (240.025 us; speedup 1.0000x reference)
//
#include <hip/hip_runtime.h>
#include <hip/hip_bf16.h>

// Problem constants
#define BB 2
#define NN 2048
#define DDIM 1024
#define HH 16
#define HDD 64

typedef __attribute__((ext_vector_type(8))) short bf16x8;
typedef __attribute__((ext_vector_type(4))) short bf16x4;
typedef __attribute__((ext_vector_type(4))) float f32x4;

__device__ inline ushort f2bf(float x) {
  __hip_bfloat16 h = __float2bfloat16(x);
  ushort u;
  __builtin_memcpy(&u, &h, 2);
  return u;
}

// ---------------- fp32 -> bf16 elementwise convert (vectorized) ----------------
__global__ __launch_bounds__(256) void cvt_f32_bf16(const float* __restrict__ in,
                                                    ushort* __restrict__ out, int n4) {
  int i = blockIdx.x * 256 + threadIdx.x;
  if (i >= n4) return;
  float4 a = ((const float4*)in)[i];
  ushort4 o;
  o.x = f2bf(a.x); o.y = f2bf(a.y); o.z = f2bf(a.z); o.w = f2bf(a.w);
  ((ushort4*)out)[i] = o;
}

// ------------- fp32 [R][C] -> bf16 [C][R] transpose+convert (32x32 tiles) -------------
__global__ __launch_bounds__(256) void transpose_cvt(const float* __restrict__ in,
                                                     ushort* __restrict__ out, int R, int C) {
  __shared__ float tile[32][33];  // +1 pad: no bank conflicts
  int bx = blockIdx.x * 32, by = blockIdx.y * 32;
  int tx = threadIdx.x, ty = threadIdx.y;
#pragma unroll
  for (int r = ty; r < 32; r += 8)
    tile[r][tx] = in[(size_t)(by + r) * C + bx + tx];
  __syncthreads();
#pragma unroll
  for (int r = ty; r < 32; r += 8)
    out[(size_t)(bx + r) * R + by + tx] = f2bf(tile[tx][r]);
}

// ---------------- bf16 GEMM: C[M][N] = A[M][K] * Bt[N][K]^T + bias ----------------
// m97-style: 128x128 tile, BK=32, 4 waves each 64x64 (4x4 frags of 16x16x32)
template <int OUT_BF16>
__global__ __launch_bounds__(256) void gemm_bt(const ushort* __restrict__ A,
                                               const ushort* __restrict__ Bt,
                                               const float* __restrict__ bias,
                                               void* __restrict__ Cv, int M, int N, int K) {
  __shared__ ushort As[128 * 32];
  __shared__ ushort Bs[128 * 32];
  const int tid = threadIdx.x;
  const int wid = tid >> 6, lane = tid & 63;
  const int c = lane & 15, g = lane >> 4;
  const int wm = (wid >> 1) * 64, wn = (wid & 1) * 64;
  const int m0 = blockIdx.y * 128, n0 = blockIdx.x * 128;
  f32x4 acc[4][4] = {};
  for (int k0 = 0; k0 < K; k0 += 32) {
    __syncthreads();
#pragma unroll
    for (int it = 0; it < 2; ++it) {
      int G = tid + it * 256;        // 512 granules of 8 bf16
      int row = G >> 2, sl = G & 3;  // row 0..127, k-slot 0..3
      *(bf16x8*)(&As[row * 32 + sl * 8]) =
          *(const bf16x8*)(A + (size_t)(m0 + row) * K + k0 + sl * 8);
      *(bf16x8*)(&Bs[row * 32 + sl * 8]) =
          *(const bf16x8*)(Bt + (size_t)(n0 + row) * K + k0 + sl * 8);
    }
    __syncthreads();
    bf16x8 af[4], bfr[4];
#pragma unroll
    for (int i = 0; i < 4; ++i) {
      af[i] = *(const bf16x8*)(&As[(wm + i * 16 + c) * 32 + g * 8]);
      bfr[i] = *(const bf16x8*)(&Bs[(wn + i * 16 + c) * 32 + g * 8]);
    }
#pragma unroll
    for (int i = 0; i < 4; ++i)
#pragma unroll
      for (int j = 0; j < 4; ++j)
        acc[i][j] = __builtin_amdgcn_mfma_f32_16x16x32_bf16(af[i], bfr[j], acc[i][j], 0, 0, 0);
  }
  // C/D layout (m89-verified): col = lane&15, row = 4*(lane>>4) + reg
#pragma unroll
  for (int i = 0; i < 4; ++i) {
#pragma unroll
    for (int j = 0; j < 4; ++j) {
      int col = n0 + wn + j * 16 + c;
      float bv = bias[col];
      int row = m0 + wm + i * 16 + g * 4;
#pragma unroll
      for (int ri = 0; ri < 4; ++ri) {
        float v = acc[i][j][ri] + bv;
        if (OUT_BF16)
          ((ushort*)Cv)[(size_t)(row + ri) * N + col] = f2bf(v);
        else
          ((float*)Cv)[(size_t)(row + ri) * N + col] = v;
      }
    }
  }
}

// ---------------- causal flash attention ----------------
// grid.x = B*H (32), grid.y = N/64 (32). Block: 4 waves, wave w owns q-rows q0=qb*64+w*16..+15.
// S^T = mfma(K_frag, Q_frag): lane (g,c) holds S^T[kv0+16f+4g+i][q0+c] -> full q-row per lane.
// PV via 16x16x16 MFMA: B-frag k-layout (4g+j) == S^T D-layout (4g+i): no P exchange.
__global__ __launch_bounds__(256) void attn_fwd(const ushort* __restrict__ QKV,
                                                ushort* __restrict__ O) {
  const int bh = blockIdx.x;
  const int b = bh >> 4, h = bh & 15;
  const int qb = blockIdx.y;
  const int tid = threadIdx.x;
  const int wid = tid >> 6, lane = tid & 63;
  const int c = lane & 15, g = lane >> 4;
  const int q0 = qb * 64 + wid * 16;
  const size_t RS = 3 * DDIM;  // 3072 row stride of QKV
  const ushort* Qb = QKV + (size_t)b * NN * RS + (size_t)h * HDD;
  const ushort* Kb = Qb + DDIM;
  const ushort* Vb = Qb + 2 * DDIM;

  __shared__ ushort Ks[64 * 64];  // [kv][d], 16B-slot XOR-swizzled per row
  __shared__ ushort Vs[64 * 64];  // V^T: [d][kv ^ ((d&7)*8)]

  // Q fragments held in registers for the whole block (B-operand, k-contiguous)
  bf16x8 qf[2];
  {
    const ushort* qrow = Qb + (size_t)(q0 + c) * RS + g * 8;
    qf[0] = *(const bf16x8*)(qrow);
    qf[1] = *(const bf16x8*)(qrow + 32);
  }
  f32x4 oacc[4] = {};  // O^T[d=16db+4g+i][q0+c]
  float m = -INFINITY, lsum = 0.f;
  const int q_abs = q0 + c;
  const int ntiles = qb + 1;

  for (int t = 0; t < ntiles; ++t) {
    const int kv0 = t * 64;
    __syncthreads();
#pragma unroll
    for (int it = 0; it < 2; ++it) {
      int u = tid + it * 256;             // 512 granules of 8 bf16
      int row = u >> 3, d0 = (u & 7) * 8; // kv row 0..63, d 0..56
      const ushort* ksrc = Kb + (size_t)(kv0 + row) * RS + d0;
      *(bf16x8*)(&Ks[row * 64 + (((d0 >> 3) ^ (row & 7)) * 8)]) = *(const bf16x8*)(ksrc);
      bf16x8 vv = *(const bf16x8*)(Vb + (size_t)(kv0 + row) * RS + d0);
#pragma unroll
      for (int e = 0; e < 8; ++e) {
        int d = d0 + e;
        Vs[d * 64 + (row ^ ((d & 7) * 8))] = (ushort)vv[e];
      }
    }
    __syncthreads();

    // S^T: 4 frags over kv (16 each), accumulate over d in 2 chunks of 32
    f32x4 s[4] = {};
#pragma unroll
    for (int f = 0; f < 4; ++f) {
      int krow = f * 16 + c;
#pragma unroll
      for (int dc = 0; dc < 2; ++dc) {
        int slot = dc * 4 + g;
        bf16x8 kf = *(const bf16x8*)(&Ks[krow * 64 + ((slot ^ (krow & 7)) * 8)]);
        s[f] = __builtin_amdgcn_mfma_f32_16x16x32_bf16(kf, qf[dc], s[f], 0, 0, 0);
      }
    }

    // mask + scale + online softmax (per-lane row, cross-g reduce via shfl)
    float pmax = -INFINITY;
#pragma unroll
    for (int f = 0; f < 4; ++f)
#pragma unroll
      for (int i = 0; i < 4; ++i) {
        int kv_abs = kv0 + f * 16 + g * 4 + i;
        float sv = (kv_abs > q_abs) ? -INFINITY : s[f][i] * 0.125f;
        s[f][i] = sv;
        pmax = fmaxf(pmax, sv);
      }
    pmax = fmaxf(pmax, __shfl_xor(pmax, 16));
    pmax = fmaxf(pmax, __shfl_xor(pmax, 32));
    float mnew = fmaxf(m, pmax);
    float corr = __expf(m - mnew);  // first tile: exp(-inf)=0, oacc/lsum already 0
    float psum = 0.f;
#pragma unroll
    for (int f = 0; f < 4; ++f)
#pragma unroll
      for (int i = 0; i < 4; ++i) {
        float p = __expf(s[f][i] - mnew);
        s[f][i] = p;
        psum += p;
      }
    psum += __shfl_xor(psum, 16);
    psum += __shfl_xor(psum, 32);
    lsum = lsum * corr + psum;
    m = mnew;
#pragma unroll
    for (int db = 0; db < 4; ++db) {
      oacc[db][0] *= corr; oacc[db][1] *= corr;
      oacc[db][2] *= corr; oacc[db][3] *= corr;
    }

    // PV: O^T += V^T * P^T, K=16 chunks (f), A = V^T from swizzled LDS, B = own p values
#pragma unroll
    for (int f = 0; f < 4; ++f) {
      bf16x4 pb;
      pb[0] = (short)f2bf(s[f][0]);
      pb[1] = (short)f2bf(s[f][1]);
      pb[2] = (short)f2bf(s[f][2]);
      pb[3] = (short)f2bf(s[f][3]);
#pragma unroll
      for (int db = 0; db < 4; ++db) {
        int d = db * 16 + c;
        int sw = (f * 16 + g * 4) ^ ((d & 7) * 8);
        bf16x4 vf = *(const bf16x4*)(&Vs[d * 64 + sw]);
        oacc[db] = __builtin_amdgcn_mfma_f32_16x16x16bf16_1k(vf, pb, oacc[db], 0, 0, 0);
      }
    }
  }

  float invl = 1.f / lsum;
  ushort* orow = O + (size_t)(b * NN + q0 + c) * DDIM + h * HDD;
#pragma unroll
  for (int db = 0; db < 4; ++db) {
    ushort4 ov;
    ov.x = f2bf(oacc[db][0] * invl);
    ov.y = f2bf(oacc[db][1] * invl);
    ov.z = f2bf(oacc[db][2] * invl);
    ov.w = f2bf(oacc[db][3] * invl);
    *(ushort4*)(&orow[db * 16 + g * 4]) = ov;
  }
}

extern "C" void kernel_launch(void* const* d_in, const int* in_sizes, int n_in,
                              void* d_out, int out_size, void* d_ws, size_t ws_size,
                              hipStream_t stream) {
  const float* hidden = (const float*)d_in[0];  // [B,N,D]
  const float* W_attn = (const float*)d_in[1];  // [D,3D]
  const float* b_attn = (const float*)d_in[2];  // [3D]
  const float* W_proj = (const float*)d_in[3];  // [D,D]
  const float* b_proj = (const float*)d_in[4];  // [D]

  char* ws = (char*)d_ws;
  ushort* hbf  = (ushort*)(ws);                         // 8 MB  hidden bf16 [4096][1024]
  ushort* WaT  = (ushort*)(ws + (size_t)(8 << 20));     // 6 MB  W_attn^T bf16 [3072][1024]
  ushort* WpT  = (ushort*)(ws + (size_t)(14 << 20));    // 2 MB  W_proj^T bf16 [1024][1024]
  ushort* qkv  = (ushort*)(ws + (size_t)(16 << 20));    // 24 MB QKV bf16 [4096][3072]
  ushort* aout = (ushort*)(ws + (size_t)(40 << 20));    // 8 MB  attn out bf16 [4096][1024]

  cvt_f32_bf16<<<4096, 256, 0, stream>>>(hidden, hbf, (BB * NN * DDIM) / 4);
  transpose_cvt<<<dim3(96, 32), dim3(32, 8), 0, stream>>>(W_attn, WaT, 1024, 3072);
  transpose_cvt<<<dim3(32, 32), dim3(32, 8), 0, stream>>>(W_proj, WpT, 1024, 1024);

  gemm_bt<1><<<dim3(24, 32), 256, 0, stream>>>(hbf, WaT, b_attn, qkv, 4096, 3072, 1024);
  attn_fwd<<<dim3(32, 32), 256, 0, stream>>>(qkv, aout);
  gemm_bt<0><<<dim3(8, 32), 256, 0, stream>>>(aout, WpT, b_proj, d_out, 4096, 1024, 1024);
}

// Round 4
// 230.119 us; speedup vs baseline: 1.0430x; 1.0430x over previous
//
#include <hip/hip_runtime.h>
#include <hip/hip_bf16.h>

// Problem constants
#define BB 2
#define NN 2048
#define DDIM 1024
#define HH 16
#define HDD 64

typedef __attribute__((ext_vector_type(8))) short bf16x8;
typedef __attribute__((ext_vector_type(4))) short bf16x4;
typedef __attribute__((ext_vector_type(4))) float f32x4;

__device__ inline ushort f2bf(float x) {
  __hip_bfloat16 h = __float2bfloat16(x);
  ushort u;
  __builtin_memcpy(&u, &h, 2);
  return u;
}

// async global->LDS, 16B per lane; LDS dest must be wave-uniform-base + lane*16
#define GLOAD_LDS16(g, l)                                                            \
  __builtin_amdgcn_global_load_lds((const __attribute__((address_space(1))) void*)(g), \
                                   (__attribute__((address_space(3))) void*)(l), 16, 0, 0)

// ---------------- fp32 -> bf16 elementwise convert (vectorized) ----------------
__global__ __launch_bounds__(256) void cvt_f32_bf16(const float* __restrict__ in,
                                                    ushort* __restrict__ out, int n4) {
  int i = blockIdx.x * 256 + threadIdx.x;
  if (i >= n4) return;
  float4 a = ((const float4*)in)[i];
  ushort4 o;
  o.x = f2bf(a.x); o.y = f2bf(a.y); o.z = f2bf(a.z); o.w = f2bf(a.w);
  ((ushort4*)out)[i] = o;
}

// ------------- fp32 [R][C] -> bf16 [C][R] transpose+convert (32x32 tiles) -------------
__global__ __launch_bounds__(256) void transpose_cvt(const float* __restrict__ in,
                                                     ushort* __restrict__ out, int R, int C) {
  __shared__ float tile[32][33];
  int bx = blockIdx.x * 32, by = blockIdx.y * 32;
  int tx = threadIdx.x, ty = threadIdx.y;
#pragma unroll
  for (int r = ty; r < 32; r += 8)
    tile[r][tx] = in[(size_t)(by + r) * C + bx + tx];
  __syncthreads();
#pragma unroll
  for (int r = ty; r < 32; r += 8)
    out[(size_t)(bx + r) * R + by + tx] = f2bf(tile[tx][r]);
}

// ---------------- bf16 GEMM: C[M][N] = A[M][K] * Bt[N][K]^T + bias ----------------
// 128x128 tile, BK=32, 4 waves each 64x64, global_load_lds(16B) staging (m97 structure).
// MODE 0: float out. MODE 1: bf16 out. MODE 2: QKV split — cols<2048 -> qk[row][2048],
//         cols>=2048 (the V block) written TRANSPOSED to Vt[bh][d][n] (ushort4 stores).
template <int MODE>
__global__ __launch_bounds__(256) void gemm_bt(const ushort* __restrict__ A,
                                               const ushort* __restrict__ Bt,
                                               const float* __restrict__ bias,
                                               void* __restrict__ Cv,
                                               ushort* __restrict__ Vt,
                                               int M, int N, int K) {
  __shared__ ushort As[128 * 32];
  __shared__ ushort Bs[128 * 32];
  const int tid = threadIdx.x;
  const int wid = tid >> 6, lane = tid & 63;
  const int c = lane & 15, g = lane >> 4;
  const int wm = (wid >> 1) * 64, wn = (wid & 1) * 64;
  const int m0 = blockIdx.y * 128, n0 = blockIdx.x * 128;
  f32x4 acc[4][4] = {};
  for (int k0 = 0; k0 < K; k0 += 32) {
    __syncthreads();
#pragma unroll
    for (int it = 0; it < 2; ++it) {
      int G = tid + it * 256;        // granule id: row = G>>2, k-slot = G&3
      int row = G >> 2, sl = G & 3;
      GLOAD_LDS16(A + (size_t)(m0 + row) * K + k0 + sl * 8, &As[G * 8]);
      GLOAD_LDS16(Bt + (size_t)(n0 + row) * K + k0 + sl * 8, &Bs[G * 8]);
    }
    __syncthreads();  // compiler emits vmcnt(0) drain here
    bf16x8 af[4], bfr[4];
#pragma unroll
    for (int i = 0; i < 4; ++i) {
      af[i] = *(const bf16x8*)(&As[(wm + i * 16 + c) * 32 + g * 8]);
      bfr[i] = *(const bf16x8*)(&Bs[(wn + i * 16 + c) * 32 + g * 8]);
    }
#pragma unroll
    for (int i = 0; i < 4; ++i)
#pragma unroll
      for (int j = 0; j < 4; ++j)
        acc[i][j] = __builtin_amdgcn_mfma_f32_16x16x32_bf16(af[i], bfr[j], acc[i][j], 0, 0, 0);
  }
  // C/D layout: col = lane&15, row = 4*(lane>>4) + reg
#pragma unroll
  for (int i = 0; i < 4; ++i) {
#pragma unroll
    for (int j = 0; j < 4; ++j) {
      const int col = n0 + wn + j * 16 + c;
      const float bv = bias[col];
      const int row = m0 + wm + i * 16 + g * 4;
      if (MODE == 2 && col >= 2048) {
        // V block: write transposed. acc[..][ri] varies along n -> contiguous in Vt.
        const int hh = (col - 2048) >> 6, dd = (col - 2048) & 63;
        const int bb = row >> 11, nl = row & 2047;
        ushort4 ov;
        ov.x = f2bf(acc[i][j][0] + bv);
        ov.y = f2bf(acc[i][j][1] + bv);
        ov.z = f2bf(acc[i][j][2] + bv);
        ov.w = f2bf(acc[i][j][3] + bv);
        *(ushort4*)(&Vt[(size_t)((bb * 16 + hh) * 64 + dd) * NN + nl]) = ov;
      } else {
        const int ldc = (MODE == 2) ? 2048 : N;
#pragma unroll
        for (int ri = 0; ri < 4; ++ri) {
          float v = acc[i][j][ri] + bv;
          if (MODE == 0)
            ((float*)Cv)[(size_t)(row + ri) * ldc + col] = v;
          else
            ((ushort*)Cv)[(size_t)(row + ri) * ldc + col] = f2bf(v);
        }
      }
    }
  }
}

// ---------------- causal flash attention ----------------
// QK buffer: [B*N][2048] bf16 (Q cols h*64+d, K cols 1024+h*64+d). Vt: [B*H][64][N] bf16.
// grid.x = B*H (32), grid.y = N/64 (32), heavy q-blocks first. 4 waves; wave w owns q-rows
// q0 = qb*64 + w*16 .. +15.
// S^T = mfma16x16x32(K_frag, Q_frag): lane (c,g) holds S^T[kv=16f+4g+i][q0+c].
// PV:  O^T = mfma16x16x16(V^T_frag, P^T): B-frag k-layout (4g+j) == S^T D-layout -> P stays
// in-register; V^T frags are bf16x4 reads from XOR-swizzled Vs (staged vectorized from Vt).
__global__ __launch_bounds__(256) void attn_fwd(const ushort* __restrict__ QK,
                                                const ushort* __restrict__ Vt,
                                                ushort* __restrict__ O) {
  const int bh = blockIdx.x;
  const int b = bh >> 4, h = bh & 15;
  const int qb = (int)gridDim.y - 1 - (int)blockIdx.y;  // heavy blocks dispatch first
  const int tid = threadIdx.x;
  const int wid = tid >> 6, lane = tid & 63;
  const int c = lane & 15, g = lane >> 4;
  const int q0 = qb * 64 + wid * 16;
  const ushort* Qb = QK + (size_t)b * NN * 2048 + (size_t)h * HDD;
  const ushort* Kb = Qb + 1024;
  const ushort* Vb = Vt + (size_t)bh * HDD * NN;

  __shared__ ushort Ks[64 * 64];  // [kv][d], 16B-slot XOR swizzle: slot ^= (kv&7)
  __shared__ ushort Vs[64 * 64];  // V^T [d][kv], 16B-slot XOR swizzle: slot ^= (d&7)

  bf16x8 qf[2];
  {
    const ushort* qrow = Qb + (size_t)(q0 + c) * 2048 + g * 8;
    qf[0] = *(const bf16x8*)(qrow);
    qf[1] = *(const bf16x8*)(qrow + 32);
  }
  f32x4 oacc[4] = {};  // O^T[d = 16db + 4g + i][q0+c]
  float m = -INFINITY, lsum = 0.f;
  const int q_abs = q0 + c;
  const int ntiles = qb + 1;

  for (int t = 0; t < ntiles; ++t) {
    const int kv0 = t * 64;
    __syncthreads();
#pragma unroll
    for (int it = 0; it < 2; ++it) {
      int u = tid + it * 256;
      int row = u >> 3, sl = u & 7;  // row: kv for Ks, d for Vs
      *(bf16x8*)(&Ks[row * 64 + ((sl ^ (row & 7)) * 8)]) =
          *(const bf16x8*)(Kb + (size_t)(kv0 + row) * 2048 + sl * 8);
      *(bf16x8*)(&Vs[row * 64 + ((sl ^ (row & 7)) * 8)]) =
          *(const bf16x8*)(Vb + (size_t)row * NN + kv0 + sl * 8);
    }
    __syncthreads();

    // S^T: 4 kv-frags x 2 d-chunks of 32
    f32x4 s[4] = {};
#pragma unroll
    for (int f = 0; f < 4; ++f) {
      int krow = f * 16 + c;
#pragma unroll
      for (int dc = 0; dc < 2; ++dc) {
        int slot = dc * 4 + g;
        bf16x8 kf = *(const bf16x8*)(&Ks[krow * 64 + ((slot ^ (krow & 7)) * 8)]);
        s[f] = __builtin_amdgcn_mfma_f32_16x16x32_bf16(kf, qf[dc], s[f], 0, 0, 0);
      }
    }

    // mask + scale + online softmax (full q-row per lane; cross-g reduce via shfl)
    float pmax = -INFINITY;
#pragma unroll
    for (int f = 0; f < 4; ++f)
#pragma unroll
      for (int i = 0; i < 4; ++i) {
        int kv_abs = kv0 + f * 16 + g * 4 + i;
        float sv = (kv_abs > q_abs) ? -INFINITY : s[f][i] * 0.125f;
        s[f][i] = sv;
        pmax = fmaxf(pmax, sv);
      }
    pmax = fmaxf(pmax, __shfl_xor(pmax, 16));
    pmax = fmaxf(pmax, __shfl_xor(pmax, 32));
    float mnew = fmaxf(m, pmax);
    float corr = __expf(m - mnew);
    float psum = 0.f;
#pragma unroll
    for (int f = 0; f < 4; ++f)
#pragma unroll
      for (int i = 0; i < 4; ++i) {
        float p = __expf(s[f][i] - mnew);
        s[f][i] = p;
        psum += p;
      }
    psum += __shfl_xor(psum, 16);
    psum += __shfl_xor(psum, 32);
    lsum = lsum * corr + psum;
    m = mnew;
#pragma unroll
    for (int db = 0; db < 4; ++db) {
      oacc[db][0] *= corr; oacc[db][1] *= corr;
      oacc[db][2] *= corr; oacc[db][3] *= corr;
    }

    // PV: O^T += V^T * P^T  (K=16 chunks over f)
#pragma unroll
    for (int f = 0; f < 4; ++f) {
      bf16x4 pb;
      pb[0] = (short)f2bf(s[f][0]);
      pb[1] = (short)f2bf(s[f][1]);
      pb[2] = (short)f2bf(s[f][2]);
      pb[3] = (short)f2bf(s[f][3]);
      const int slot = f * 2 + (g >> 1);
#pragma unroll
      for (int db = 0; db < 4; ++db) {
        int d = db * 16 + c;
        bf16x4 vf = *(const bf16x4*)(&Vs[d * 64 + ((slot ^ (d & 7)) * 8) + (g & 1) * 4]);
        oacc[db] = __builtin_amdgcn_mfma_f32_16x16x16bf16_1k(vf, pb, oacc[db], 0, 0, 0);
      }
    }
  }

  float invl = 1.f / lsum;
  ushort* orow = O + (size_t)(b * NN + q0 + c) * DDIM + h * HDD;
#pragma unroll
  for (int db = 0; db < 4; ++db) {
    ushort4 ov;
    ov.x = f2bf(oacc[db][0] * invl);
    ov.y = f2bf(oacc[db][1] * invl);
    ov.z = f2bf(oacc[db][2] * invl);
    ov.w = f2bf(oacc[db][3] * invl);
    *(ushort4*)(&orow[db * 16 + g * 4]) = ov;
  }
}

extern "C" void kernel_launch(void* const* d_in, const int* in_sizes, int n_in,
                              void* d_out, int out_size, void* d_ws, size_t ws_size,
                              hipStream_t stream) {
  const float* hidden = (const float*)d_in[0];  // [B,N,D]
  const float* W_attn = (const float*)d_in[1];  // [D,3D]
  const float* b_attn = (const float*)d_in[2];  // [3D]
  const float* W_proj = (const float*)d_in[3];  // [D,D]
  const float* b_proj = (const float*)d_in[4];  // [D]

  char* ws = (char*)d_ws;
  ushort* hbf  = (ushort*)(ws);                       // 8 MB  hidden bf16 [4096][1024]
  ushort* WaT  = (ushort*)(ws + (size_t)(8 << 20));   // 6 MB  W_attn^T bf16 [3072][1024]
  ushort* WpT  = (ushort*)(ws + (size_t)(14 << 20));  // 2 MB  W_proj^T bf16 [1024][1024]
  ushort* qk   = (ushort*)(ws + (size_t)(16 << 20));  // 16 MB Q|K bf16 [4096][2048]
  ushort* vt   = (ushort*)(ws + (size_t)(32 << 20));  // 8 MB  V^T bf16 [32][64][2048]
  ushort* aout = (ushort*)(ws + (size_t)(40 << 20));  // 8 MB  attn out bf16 [4096][1024]

  cvt_f32_bf16<<<4096, 256, 0, stream>>>(hidden, hbf, (BB * NN * DDIM) / 4);
  transpose_cvt<<<dim3(96, 32), dim3(32, 8), 0, stream>>>(W_attn, WaT, 1024, 3072);
  transpose_cvt<<<dim3(32, 32), dim3(32, 8), 0, stream>>>(W_proj, WpT, 1024, 1024);

  gemm_bt<2><<<dim3(24, 32), 256, 0, stream>>>(hbf, WaT, b_attn, qk, vt, 4096, 3072, 1024);
  attn_fwd<<<dim3(32, 32), 256, 0, stream>>>(qk, vt, aout);
  gemm_bt<0><<<dim3(8, 32), 256, 0, stream>>>(aout, WpT, b_proj, d_out, nullptr, 4096, 1024, 1024);
}

// Round 6
// 191.020 us; speedup vs baseline: 1.2565x; 1.2047x over previous
//
#include <hip/hip_runtime.h>
#include <hip/hip_bf16.h>

// Problem constants
#define BB 2
#define NN 2048
#define DDIM 1024
#define HH 16
#define HDD 64

typedef __attribute__((ext_vector_type(8))) short bf16x8;
typedef __attribute__((ext_vector_type(4))) short bf16x4;
typedef __attribute__((ext_vector_type(4))) float f32x4;

__device__ inline ushort f2bf(float x) {
  __hip_bfloat16 h = __float2bfloat16(x);
  ushort u;
  __builtin_memcpy(&u, &h, 2);
  return u;
}
__device__ inline float bf2f(ushort u) {
  unsigned v = (unsigned)u << 16;
  float f;
  __builtin_memcpy(&f, &v, 4);
  return f;
}
// raw v_exp_f32: computes 2^x (1 instr; no libm denorm branches)
__device__ inline float exp2_raw(float x) {
  float r;
  asm("v_exp_f32 %0, %1" : "=v"(r) : "v"(x));
  return r;
}

// async global->LDS, 16B per lane; LDS dest must be wave-uniform-base + lane*16
#define GLOAD_LDS16(g, l)                                                              \
  __builtin_amdgcn_global_load_lds((const __attribute__((address_space(1))) void*)(g), \
                                   (__attribute__((address_space(3))) void*)(l), 16, 0, 0)

// ---------------- fp32 -> bf16 elementwise convert (vectorized) ----------------
__global__ __launch_bounds__(256) void cvt_f32_bf16(const float* __restrict__ in,
                                                    ushort* __restrict__ out, int n4) {
  int i = blockIdx.x * 256 + threadIdx.x;
  if (i >= n4) return;
  float4 a = ((const float4*)in)[i];
  ushort4 o;
  o.x = f2bf(a.x); o.y = f2bf(a.y); o.z = f2bf(a.z); o.w = f2bf(a.w);
  ((ushort4*)out)[i] = o;
}

// ------------- fp32 [R][C] -> bf16 [C][R] transpose+convert (32x32 tiles) -------------
__global__ __launch_bounds__(256) void transpose_cvt(const float* __restrict__ in,
                                                     ushort* __restrict__ out, int R, int C) {
  __shared__ float tile[32][33];
  int bx = blockIdx.x * 32, by = blockIdx.y * 32;
  int tx = threadIdx.x, ty = threadIdx.y;
#pragma unroll
  for (int r = ty; r < 32; r += 8)
    tile[r][tx] = in[(size_t)(by + r) * C + bx + tx];
  __syncthreads();
#pragma unroll
  for (int r = ty; r < 32; r += 8)
    out[(size_t)(bx + r) * R + by + tx] = f2bf(tile[tx][r]);
}

// ---------------- bf16 GEMM: C[M][N] = A[M][K] * Bt[N][K]^T + bias ----------------
// 128x128 tile, BK=32, 4 waves each 64x64, global_load_lds(16B) staging (m97 structure).
// MODE 1: bf16 out. MODE 2: QKV split — cols<2048 -> qk[row][2048],
//         cols>=2048 (the V block) written TRANSPOSED to Vt[bh][d][n] (ushort4 stores).
template <int MODE>
__global__ __launch_bounds__(256) void gemm_bt(const ushort* __restrict__ A,
                                               const ushort* __restrict__ Bt,
                                               const float* __restrict__ bias,
                                               void* __restrict__ Cv,
                                               ushort* __restrict__ Vt,
                                               int M, int N, int K) {
  __shared__ ushort As[128 * 32];
  __shared__ ushort Bs[128 * 32];
  const int tid = threadIdx.x;
  const int wid = tid >> 6, lane = tid & 63;
  const int c = lane & 15, g = lane >> 4;
  const int wm = (wid >> 1) * 64, wn = (wid & 1) * 64;
  const int m0 = blockIdx.y * 128, n0 = blockIdx.x * 128;
  f32x4 acc[4][4] = {};
  for (int k0 = 0; k0 < K; k0 += 32) {
    __syncthreads();
#pragma unroll
    for (int it = 0; it < 2; ++it) {
      int G = tid + it * 256;
      int row = G >> 2, sl = G & 3;
      GLOAD_LDS16(A + (size_t)(m0 + row) * K + k0 + sl * 8, &As[G * 8]);
      GLOAD_LDS16(Bt + (size_t)(n0 + row) * K + k0 + sl * 8, &Bs[G * 8]);
    }
    __syncthreads();
    bf16x8 af[4], bfr[4];
#pragma unroll
    for (int i = 0; i < 4; ++i) {
      af[i] = *(const bf16x8*)(&As[(wm + i * 16 + c) * 32 + g * 8]);
      bfr[i] = *(const bf16x8*)(&Bs[(wn + i * 16 + c) * 32 + g * 8]);
    }
#pragma unroll
    for (int i = 0; i < 4; ++i)
#pragma unroll
      for (int j = 0; j < 4; ++j)
        acc[i][j] = __builtin_amdgcn_mfma_f32_16x16x32_bf16(af[i], bfr[j], acc[i][j], 0, 0, 0);
  }
#pragma unroll
  for (int i = 0; i < 4; ++i) {
#pragma unroll
    for (int j = 0; j < 4; ++j) {
      const int col = n0 + wn + j * 16 + c;
      const float bv = bias[col];
      const int row = m0 + wm + i * 16 + g * 4;
      if (MODE == 2 && col >= 2048) {
        const int hh = (col - 2048) >> 6, dd = (col - 2048) & 63;
        const int bb = row >> 11, nl = row & 2047;
        ushort4 ov;
        ov.x = f2bf(acc[i][j][0] + bv);
        ov.y = f2bf(acc[i][j][1] + bv);
        ov.z = f2bf(acc[i][j][2] + bv);
        ov.w = f2bf(acc[i][j][3] + bv);
        *(ushort4*)(&Vt[(size_t)((bb * 16 + hh) * 64 + dd) * NN + nl]) = ov;
      } else {
        const int ldc = (MODE == 2) ? 2048 : N;
#pragma unroll
        for (int ri = 0; ri < 4; ++ri) {
          float v = acc[i][j][ri] + bv;
          ((ushort*)Cv)[(size_t)(row + ri) * ldc + col] = f2bf(v);
        }
      }
    }
  }
}

// ---------------- proj GEMM (float out), 64x128 tile for 2 blocks/CU occupancy ------
// grid (N/128, M/64). 4 waves side-by-side over N=128 (each 64x32), acc[4][2].
__global__ __launch_bounds__(256) void gemm_proj(const ushort* __restrict__ A,
                                                 const ushort* __restrict__ Bt,
                                                 const float* __restrict__ bias,
                                                 float* __restrict__ C, int M, int N, int K) {
  __shared__ ushort As[64 * 32];
  __shared__ ushort Bs[128 * 32];
  const int tid = threadIdx.x;
  const int wid = tid >> 6, lane = tid & 63;
  const int c = lane & 15, g = lane >> 4;
  const int wn = wid * 32;
  const int m0 = blockIdx.y * 64, n0 = blockIdx.x * 128;
  f32x4 acc[4][2] = {};
  for (int k0 = 0; k0 < K; k0 += 32) {
    __syncthreads();
#pragma unroll
    for (int it = 0; it < 3; ++it) {
      int G = tid + it * 256;  // 0..255: A granules (64 rows x 4 slots); 256..767: B
      if (G < 256) {
        int row = G >> 2, sl = G & 3;
        GLOAD_LDS16(A + (size_t)(m0 + row) * K + k0 + sl * 8, &As[G * 8]);
      } else {
        int GB = G - 256;
        int row = GB >> 2, sl = GB & 3;
        GLOAD_LDS16(Bt + (size_t)(n0 + row) * K + k0 + sl * 8, &Bs[GB * 8]);
      }
    }
    __syncthreads();
    bf16x8 af[4], bfr[2];
#pragma unroll
    for (int i = 0; i < 4; ++i) af[i] = *(const bf16x8*)(&As[(i * 16 + c) * 32 + g * 8]);
#pragma unroll
    for (int j = 0; j < 2; ++j)
      bfr[j] = *(const bf16x8*)(&Bs[(wn + j * 16 + c) * 32 + g * 8]);
#pragma unroll
    for (int i = 0; i < 4; ++i)
#pragma unroll
      for (int j = 0; j < 2; ++j)
        acc[i][j] = __builtin_amdgcn_mfma_f32_16x16x32_bf16(af[i], bfr[j], acc[i][j], 0, 0, 0);
  }
#pragma unroll
  for (int i = 0; i < 4; ++i) {
#pragma unroll
    for (int j = 0; j < 2; ++j) {
      const int col = n0 + wn + j * 16 + c;
      const float bv = bias[col];
      const int row = m0 + i * 16 + g * 4;
#pragma unroll
      for (int ri = 0; ri < 4; ++ri)
        C[(size_t)(row + ri) * N + col] = acc[i][j][ri] + bv;
    }
  }
}

// ---------------- causal flash attention (2-phase dbuf, log2-domain softmax) --------
// QK: [B*N][2048] bf16 (Q cols h*64+d, K cols 1024+h*64+d). Vt: [B*H][64][N] bf16.
// grid.x = B*H (32), grid.y = N/64 (32). 4 waves; wave w owns q-rows q0=qb*64+w*16..+15.
// S^T = mfma16x16x32(K, Q): lane (c,g) holds S^T[kv=16f+4g+i][q0+c] -> full q-row/lane.
// PV = mfma16x16x16(V^T, P^T): B-frag k-layout matches S^T D-layout -> P in-register.
// Staging: global_load_lds(16B) w/ pre-swizzled SOURCE (linear LDS dest, rule #21);
// double-buffered, ONE barrier/tile (T3-minimum). Q pre-scaled by 0.125*log2(e);
// defer-max (T13, THR=8 in log2 => P<=256); lane-local lsum reduced once at end.
__global__ __launch_bounds__(256) void attn_fwd(const ushort* __restrict__ QK,
                                                const ushort* __restrict__ Vt,
                                                ushort* __restrict__ O) {
  const int bh = blockIdx.x;
  const int b = bh >> 4, h = bh & 15;
  const int qb = (int)gridDim.y - 1 - (int)blockIdx.y;
  const int tid = threadIdx.x;
  const int wid = tid >> 6, lane = tid & 63;
  const int c = lane & 15, g = lane >> 4;
  const int q0 = qb * 64 + wid * 16;
  const ushort* Qb = QK + (size_t)b * NN * 2048 + (size_t)h * HDD;
  const ushort* Kb = Qb + 1024;
  const ushort* Vb = Vt + (size_t)bh * HDD * NN;

  __shared__ ushort Ks[2][64 * 64];  // linear [row][slot*8]; content XOR-swizzled via src
  __shared__ ushort Vs[2][64 * 64];

  // Q fragments, pre-scaled by 0.125 * log2(e)
  const float SC = 0.18033688011112042f;
  bf16x8 qf[2];
  {
    const ushort* qrow = Qb + (size_t)(q0 + c) * 2048 + g * 8;
    qf[0] = *(const bf16x8*)(qrow);
    qf[1] = *(const bf16x8*)(qrow + 32);
#pragma unroll
    for (int r = 0; r < 2; ++r)
#pragma unroll
      for (int e = 0; e < 8; ++e) qf[r][e] = (short)f2bf(bf2f((ushort)qf[r][e]) * SC);
  }

  f32x4 oacc[4] = {};  // O^T[d = 16db + 4g + i][q0+c]
  float m = 0.f, lsum = 0.f;  // m in log2 domain
  const int q_abs = q0 + c;

  // stage tile kv0 into buffer bufi: K rows + V^T rows, source pre-swizzled
#define STAGE_TILE(kv0, bufi)                                                   \
  do {                                                                          \
    _Pragma("unroll") for (int it = 0; it < 2; ++it) {                          \
      int u = tid + it * 256;                                                   \
      int row = u >> 3, sl = u & 7;                                             \
      int ksl = (sl ^ (row & 7)) * 8;                                           \
      GLOAD_LDS16(Kb + (size_t)((kv0) + row) * 2048 + ksl, &Ks[bufi][u * 8]);   \
      GLOAD_LDS16(Vb + (size_t)row * NN + (kv0) + ksl, &Vs[bufi][u * 8]);       \
    }                                                                           \
  } while (0)

  STAGE_TILE(0, 0);
  __syncthreads();
  int cur = 0;

  for (int t = 0; t <= qb; ++t) {
    if (t < qb) STAGE_TILE((t + 1) * 64, cur ^ 1);  // prefetch overlaps compute

    // S^T: 4 kv-frags x 2 d-chunks of 32 (values already log2-scaled via Q)
    f32x4 s[4] = {};
#pragma unroll
    for (int f = 0; f < 4; ++f) {
      int krow = f * 16 + c;
#pragma unroll
      for (int dc = 0; dc < 2; ++dc) {
        int slot = (dc * 4 + g) ^ (krow & 7);
        bf16x8 kf = *(const bf16x8*)(&Ks[cur][krow * 64 + slot * 8]);
        s[f] = __builtin_amdgcn_mfma_f32_16x16x32_bf16(kf, qf[dc], s[f], 0, 0, 0);
      }
    }

    // local max (mask only on diagonal tile; branch is block-uniform)
    float pmax = -INFINITY;
    if (t == qb) {
      const int kv0 = t * 64;
#pragma unroll
      for (int f = 0; f < 4; ++f)
#pragma unroll
        for (int i = 0; i < 4; ++i) {
          if (kv0 + f * 16 + g * 4 + i > q_abs) s[f][i] = -INFINITY;
          pmax = fmaxf(pmax, s[f][i]);
        }
    } else {
#pragma unroll
      for (int f = 0; f < 4; ++f)
#pragma unroll
        for (int i = 0; i < 4; ++i) pmax = fmaxf(pmax, s[f][i]);
    }

    // defer-max: full cross-lane reduce + rescale only when needed
    if (t == 0) {
      float pr = fmaxf(pmax, __shfl_xor(pmax, 16));
      pr = fmaxf(pr, __shfl_xor(pr, 32));
      m = pr;
    } else if (!__all(pmax <= m + 8.f)) {
      float pr = fmaxf(pmax, __shfl_xor(pmax, 16));
      pr = fmaxf(pr, __shfl_xor(pr, 32));
      float mnew = fmaxf(m, pr);
      float corr = exp2_raw(m - mnew);
      lsum *= corr;
#pragma unroll
      for (int db = 0; db < 4; ++db) {
        oacc[db][0] *= corr; oacc[db][1] *= corr;
        oacc[db][2] *= corr; oacc[db][3] *= corr;
      }
      m = mnew;
    }

    float psum = 0.f;
#pragma unroll
    for (int f = 0; f < 4; ++f)
#pragma unroll
      for (int i = 0; i < 4; ++i) {
        float p = exp2_raw(s[f][i] - m);
        s[f][i] = p;
        psum += p;
      }
    lsum += psum;  // lane-local partial; cross-g reduce deferred to epilogue

    // PV: O^T += V^T * P^T  (K=16 chunks over f)
#pragma unroll
    for (int f = 0; f < 4; ++f) {
      bf16x4 pb;
      pb[0] = (short)f2bf(s[f][0]);
      pb[1] = (short)f2bf(s[f][1]);
      pb[2] = (short)f2bf(s[f][2]);
      pb[3] = (short)f2bf(s[f][3]);
      const int slot = f * 2 + (g >> 1);
#pragma unroll
      for (int db = 0; db < 4; ++db) {
        int d = db * 16 + c;
        bf16x4 vf =
            *(const bf16x4*)(&Vs[cur][d * 64 + ((slot ^ (d & 7)) * 8) + (g & 1) * 4]);
        oacc[db] = __builtin_amdgcn_mfma_f32_16x16x16bf16_1k(vf, pb, oacc[db], 0, 0, 0);
      }
    }
    __syncthreads();  // drains prefetch vmcnt + releases cur buffer
    cur ^= 1;
  }

  lsum += __shfl_xor(lsum, 16);
  lsum += __shfl_xor(lsum, 32);
  float invl = 1.f / lsum;
  ushort* orow = O + (size_t)(b * NN + q0 + c) * DDIM + h * HDD;
#pragma unroll
  for (int db = 0; db < 4; ++db) {
    ushort4 ov;
    ov.x = f2bf(oacc[db][0] * invl);
    ov.y = f2bf(oacc[db][1] * invl);
    ov.z = f2bf(oacc[db][2] * invl);
    ov.w = f2bf(oacc[db][3] * invl);
    *(ushort4*)(&orow[db * 16 + g * 4]) = ov;
  }
}

extern "C" void kernel_launch(void* const* d_in, const int* in_sizes, int n_in,
                              void* d_out, int out_size, void* d_ws, size_t ws_size,
                              hipStream_t stream) {
  const float* hidden = (const float*)d_in[0];  // [B,N,D]
  const float* W_attn = (const float*)d_in[1];  // [D,3D]
  const float* b_attn = (const float*)d_in[2];  // [3D]
  const float* W_proj = (const float*)d_in[3];  // [D,D]
  const float* b_proj = (const float*)d_in[4];  // [D]

  char* ws = (char*)d_ws;
  ushort* hbf  = (ushort*)(ws);                       // 8 MB  hidden bf16 [4096][1024]
  ushort* WaT  = (ushort*)(ws + (size_t)(8 << 20));   // 6 MB  W_attn^T bf16 [3072][1024]
  ushort* WpT  = (ushort*)(ws + (size_t)(14 << 20));  // 2 MB  W_proj^T bf16 [1024][1024]
  ushort* qk   = (ushort*)(ws + (size_t)(16 << 20));  // 16 MB Q|K bf16 [4096][2048]
  ushort* vt   = (ushort*)(ws + (size_t)(32 << 20));  // 8 MB  V^T bf16 [32][64][2048]
  ushort* aout = (ushort*)(ws + (size_t)(40 << 20));  // 8 MB  attn out bf16 [4096][1024]

  cvt_f32_bf16<<<4096, 256, 0, stream>>>(hidden, hbf, (BB * NN * DDIM) / 4);
  transpose_cvt<<<dim3(96, 32), dim3(32, 8), 0, stream>>>(W_attn, WaT, 1024, 3072);
  transpose_cvt<<<dim3(32, 32), dim3(32, 8), 0, stream>>>(W_proj, WpT, 1024, 1024);

  gemm_bt<2><<<dim3(24, 32), 256, 0, stream>>>(hbf, WaT, b_attn, qk, vt, 4096, 3072, 1024);
  attn_fwd<<<dim3(32, 32), 256, 0, stream>>>(qk, vt, aout);
  gemm_proj<<<dim3(8, 64), 256, 0, stream>>>(aout, WpT, b_proj, (float*)d_out, 4096, 1024, 1024);
}